// Round 2
// baseline (1159.425 us; speedup 1.0000x reference)
//
#include <hip/hip_runtime.h>
#include <hip/hip_bf16.h>

typedef __bf16 bf16x8 __attribute__((ext_vector_type(8)));
typedef float f32x4 __attribute__((ext_vector_type(4)));

#define EPS 1e-5f

static __device__ __forceinline__ int lower_bound_i(const int* __restrict__ arr, int n, int val) {
  int lo = 0, hi = n;
  while (lo < hi) { int mid = (lo + hi) >> 1; if (arr[mid] < val) lo = mid + 1; else hi = mid; }
  return lo;
}

// ---------------- dtype detection ----------------
// flags[0]=1 if float inputs are bf16 (else fp32); flags[1]=1 if int inputs are int64 (else int32)
__global__ void detect_dtypes(const unsigned* __restrict__ xw, const unsigned* __restrict__ eiw,
                              int* __restrict__ flags) {
  __shared__ int s_bf16, s_i64nz;
  int t = threadIdx.x;
  if (t == 0) { s_bf16 = 0; s_i64nz = 0; }
  __syncthreads();
  // float probe: low 16 bits of sampled words
  unsigned w = xw[t * 97];
  unsigned lo = w & 0xFFFFu;
  unsigned e = (lo >> 7) & 0xFF;
  int looks_bf16 = (lo == 0u) || (e >= 0x6A && e <= 0x86);
  atomicAdd(&s_bf16, looks_bf16);
  // int probe: odd words (high halves if int64). k*2+1 < 800000 -> safe under both widths.
  int k = t * 1031;
  int nz = (eiw[2 * k + 1] != 0u) ? 1 : 0;
  atomicAdd(&s_i64nz, nz);
  __syncthreads();
  if (t == 0) {
    flags[0] = (s_bf16 >= 192) ? 1 : 0;
    flags[1] = (s_i64nz == 0) ? 1 : 0;
  }
}

// ---------------- canonicalization ----------------
__global__ void canon_f32(const void* __restrict__ src, float* __restrict__ dst, int n,
                          const int* __restrict__ flags) {
  int i = blockIdx.x * blockDim.x + threadIdx.x;
  if (i >= n) return;
  if (flags[0]) dst[i] = (float)((const __bf16*)src)[i];
  else          dst[i] = ((const float*)src)[i];
}

__global__ void canon_bf16(const void* __restrict__ src, __bf16* __restrict__ dst, int n,
                           const int* __restrict__ flags) {
  int i = blockIdx.x * blockDim.x + threadIdx.x;
  if (i >= n) return;
  if (flags[0]) dst[i] = ((const __bf16*)src)[i];
  else          dst[i] = (__bf16)((const float*)src)[i];
}

__global__ void f32_to_bf16(const float* __restrict__ src, __bf16* __restrict__ dst, int n) {
  int i = blockIdx.x * blockDim.x + threadIdx.x;
  if (i >= n) return;
  dst[i] = (__bf16)src[i];
}

__global__ void canon_i32(const void* __restrict__ src, int* __restrict__ dst, int n,
                          const int* __restrict__ flags) {
  int i = blockIdx.x * blockDim.x + threadIdx.x;
  if (i >= n) return;
  if (flags[1]) dst[i] = (int)((const long long*)src)[i];
  else          dst[i] = ((const int*)src)[i];
}

// ---------------- CSR build ----------------
__global__ void count_deg(const int* __restrict__ ei, int E, int N, int* __restrict__ deg) {
  int e = blockIdx.x * blockDim.x + threadIdx.x;
  if (e >= E + N) return;
  int d = (e < E) ? ei[E + e] : (e - E);
  atomicAdd(&deg[d], 1);
}

__global__ void scan_offsets(const int* __restrict__ deg, int* __restrict__ offs,
                             int* __restrict__ cursor, int N) {
  __shared__ int part[1024];
  int t = threadIdx.x;
  int chunk = (N + 1023) / 1024;
  int start = t * chunk, end = min(start + chunk, N);
  int s = 0;
  for (int i = start; i < end; i++) s += deg[i];
  part[t] = s;
  __syncthreads();
  for (int off = 1; off < 1024; off <<= 1) {
    int v = (t >= off) ? part[t - off] : 0;
    __syncthreads();
    part[t] += v;
    __syncthreads();
  }
  int run = (t == 0) ? 0 : part[t - 1];
  for (int i = start; i < end; i++) {
    offs[i] = run; cursor[i] = run; run += deg[i];
  }
  if (end == N && start < N) offs[N] = run;
}

__global__ void fill_csr(const int* __restrict__ ei, int E, int N,
                         int* __restrict__ cursor, int* __restrict__ csr_src) {
  int e = blockIdx.x * blockDim.x + threadIdx.x;
  if (e >= E + N) return;
  int s, d;
  if (e < E) { s = ei[e]; d = ei[E + e]; } else { s = e - E; d = e - E; }
  int pos = atomicAdd(&cursor[d], 1);
  csr_src[pos] = s;
}

// ---------------- GEMM: comb[n, 0:512]=xl, [512:1024]=xr ----------------
__global__ __launch_bounds__(256) void gemm_xlr(
    const __bf16* __restrict__ A, const __bf16* __restrict__ Wl,
    const __bf16* __restrict__ Wr, const float* __restrict__ bl,
    const float* __restrict__ br, __bf16* __restrict__ out, int Nrows) {
  __shared__ __bf16 As[128][72];
  __shared__ __bf16 Bs[128][72];
  const int jb = blockIdx.y; // 0..7 (0-3 -> Wl, 4-7 -> Wr)
  const __bf16* Wbase = (jb < 4) ? (Wl + (size_t)jb * 128 * 128) : (Wr + (size_t)(jb - 4) * 128 * 128);
  const float* biasbase = (jb < 4) ? (bl + jb * 128) : (br + (jb - 4) * 128);
  const int row0 = blockIdx.x * 128;
  const int tid = threadIdx.x;
  const int lane = tid & 63, wave = tid >> 6;
  const int wm = wave >> 1, wn = wave & 1;

  f32x4 zero4 = {0.f, 0.f, 0.f, 0.f};
  f32x4 acc[4][4];
#pragma unroll
  for (int mi = 0; mi < 4; mi++)
#pragma unroll
    for (int ni = 0; ni < 4; ni++) acc[mi][ni] = zero4;

  for (int kc = 0; kc < 2; kc++) {
    __syncthreads();
#pragma unroll
    for (int p = 0; p < 4; p++) {
      int r = (tid >> 3) + p * 32;
      int cg = (tid & 7) * 8;
      int gr = row0 + r;
      bf16x8 av;
      if (gr < Nrows) av = *(const bf16x8*)(A + (size_t)gr * 128 + kc * 64 + cg);
      else {
#pragma unroll
        for (int j = 0; j < 8; j++) av[j] = (__bf16)0.0f;
      }
      *(bf16x8*)(&As[r][cg]) = av;
      bf16x8 bv = *(const bf16x8*)(Wbase + (size_t)r * 128 + kc * 64 + cg);
      *(bf16x8*)(&Bs[r][cg]) = bv;
    }
    __syncthreads();
#pragma unroll
    for (int s = 0; s < 2; s++) {
      bf16x8 af[4], bfr[4];
      int kofs = s * 32 + ((lane >> 4) * 8);
#pragma unroll
      for (int i = 0; i < 4; i++) {
        af[i]  = *(const bf16x8*)(&As[wm * 64 + i * 16 + (lane & 15)][kofs]);
        bfr[i] = *(const bf16x8*)(&Bs[wn * 64 + i * 16 + (lane & 15)][kofs]);
      }
#pragma unroll
      for (int mi = 0; mi < 4; mi++)
#pragma unroll
        for (int ni = 0; ni < 4; ni++)
          acc[mi][ni] = __builtin_amdgcn_mfma_f32_16x16x32_bf16(af[mi], bfr[ni], acc[mi][ni], 0, 0, 0);
    }
  }
#pragma unroll
  for (int mi = 0; mi < 4; mi++) {
#pragma unroll
    for (int ni = 0; ni < 4; ni++) {
      int col_l = wn * 64 + ni * 16 + (lane & 15);
      int gj = jb * 128 + col_l;
      float bias = biasbase[col_l];
#pragma unroll
      for (int r = 0; r < 4; r++) {
        int row_l = wm * 64 + mi * 16 + (lane >> 4) * 4 + r;
        int gr = row0 + row_l;
        if (gr < Nrows) out[(size_t)gr * 1024 + gj] = (__bf16)(acc[mi][ni][r] + bias);
      }
    }
  }
}

// ---------------- edge logits (one wave per dst node) ----------------
__global__ __launch_bounds__(256) void edge_logits(
    const __bf16* __restrict__ comb, const float* __restrict__ att,
    const int* __restrict__ offs, const int* __restrict__ csr_src,
    float* __restrict__ logits, int N) {
  int wid = blockIdx.x * 4 + (threadIdx.x >> 6);
  int lane = threadIdx.x & 63;
  if (wid >= N) return;
  int n = wid;
  float xr[8], at[8];
  bf16x8 xrv = *(const bf16x8*)(comb + (size_t)n * 1024 + 512 + lane * 8);
  float4 a0 = *(const float4*)(att + lane * 8);
  float4 a1 = *(const float4*)(att + lane * 8 + 4);
  at[0] = a0.x; at[1] = a0.y; at[2] = a0.z; at[3] = a0.w;
  at[4] = a1.x; at[5] = a1.y; at[6] = a1.z; at[7] = a1.w;
#pragma unroll
  for (int j = 0; j < 8; j++) xr[j] = (float)xrv[j];
  int off0 = offs[n], off1 = offs[n + 1];
  int h = lane >> 4;
  for (int pos = off0; pos < off1; pos++) {
    int src = csr_src[pos];
    bf16x8 xlv = *(const bf16x8*)(comb + (size_t)src * 1024 + lane * 8);
    float t = 0.f;
#pragma unroll
    for (int j = 0; j < 8; j++) {
      float z = (float)xlv[j] + xr[j];
      float lr = z > 0.f ? z : 0.2f * z;
      t = fmaf(lr, at[j], t);
    }
    t += __shfl_xor(t, 1);
    t += __shfl_xor(t, 2);
    t += __shfl_xor(t, 4);
    t += __shfl_xor(t, 8);
    if ((lane & 15) == 0) logits[(size_t)pos * 4 + h] = t;
  }
}

// ---------------- softmax + aggregate + mean-heads + LN + relu + residual ----------------
__global__ __launch_bounds__(256) void aggregate(
    const __bf16* __restrict__ comb, const float* __restrict__ logits,
    const int* __restrict__ offs, const int* __restrict__ csr_src,
    const float* __restrict__ conv_bias, const float* __restrict__ gamma,
    const float* __restrict__ beta, float* __restrict__ h_f32,
    __bf16* __restrict__ h_bf, int N) {
  int wid = blockIdx.x * 4 + (threadIdx.x >> 6);
  int lane = threadIdx.x & 63;
  if (wid >= N) return;
  int n = wid;
  int off0 = offs[n], off1 = offs[n + 1];
  int hsel = lane >> 4;

  float4 mx = make_float4(-1e30f, -1e30f, -1e30f, -1e30f);
  for (int pos = off0; pos < off1; pos++) {
    float4 lg = *(const float4*)(logits + (size_t)pos * 4);
    mx.x = fmaxf(mx.x, lg.x); mx.y = fmaxf(mx.y, lg.y);
    mx.z = fmaxf(mx.z, lg.z); mx.w = fmaxf(mx.w, lg.w);
  }
  float4 den = make_float4(0.f, 0.f, 0.f, 0.f);
  for (int pos = off0; pos < off1; pos++) {
    float4 lg = *(const float4*)(logits + (size_t)pos * 4);
    den.x += __expf(lg.x - mx.x); den.y += __expf(lg.y - mx.y);
    den.z += __expf(lg.z - mx.z); den.w += __expf(lg.w - mx.w);
  }
  float mxh = hsel == 0 ? mx.x : hsel == 1 ? mx.y : hsel == 2 ? mx.z : mx.w;
  float dnh = hsel == 0 ? den.x : hsel == 1 ? den.y : hsel == 2 ? den.z : den.w;
  float invh = 1.0f / fmaxf(dnh, 1e-30f);

  float accv[8];
#pragma unroll
  for (int j = 0; j < 8; j++) accv[j] = 0.f;
  for (int pos = off0; pos < off1; pos++) {
    float4 lg = *(const float4*)(logits + (size_t)pos * 4);
    float lgh = hsel == 0 ? lg.x : hsel == 1 ? lg.y : hsel == 2 ? lg.z : lg.w;
    float a = __expf(lgh - mxh) * invh;
    int src = csr_src[pos];
    bf16x8 xlv = *(const bf16x8*)(comb + (size_t)src * 1024 + lane * 8);
#pragma unroll
    for (int j = 0; j < 8; j++) accv[j] = fmaf(a, (float)xlv[j], accv[j]);
  }
#pragma unroll
  for (int j = 0; j < 8; j++) {
    accv[j] += __shfl_xor(accv[j], 16);
    accv[j] += __shfl_xor(accv[j], 32);
  }
  int c0 = (lane & 15) * 8;
  float v[8];
  float s = 0.f, s2 = 0.f;
#pragma unroll
  for (int j = 0; j < 8; j++) {
    v[j] = accv[j] * 0.25f + conv_bias[c0 + j];
    s += v[j]; s2 += v[j] * v[j];
  }
  s  += __shfl_xor(s, 1);  s2 += __shfl_xor(s2, 1);
  s  += __shfl_xor(s, 2);  s2 += __shfl_xor(s2, 2);
  s  += __shfl_xor(s, 4);  s2 += __shfl_xor(s2, 4);
  s  += __shfl_xor(s, 8);  s2 += __shfl_xor(s2, 8);
  float mu = s * (1.f / 128.f);
  float var = fmaxf(s2 * (1.f / 128.f) - mu * mu, 0.f);
  float rs = rsqrtf(var + EPS);
  if (lane < 16) {
    float4 o0, o1;
    bf16x8 hb;
    float hn[8];
#pragma unroll
    for (int j = 0; j < 8; j++) {
      float o = (v[j] - mu) * rs * gamma[c0 + j] + beta[c0 + j];
      o = o > 0.f ? o : 0.f;
      hn[j] = h_f32[(size_t)n * 128 + c0 + j] + o;
      hb[j] = (__bf16)hn[j];
    }
    o0.x = hn[0]; o0.y = hn[1]; o0.z = hn[2]; o0.w = hn[3];
    o1.x = hn[4]; o1.y = hn[5]; o1.z = hn[6]; o1.w = hn[7];
    *(float4*)(h_f32 + (size_t)n * 128 + c0) = o0;
    *(float4*)(h_f32 + (size_t)n * 128 + c0 + 4) = o1;
    *(bf16x8*)(h_bf + (size_t)n * 128 + c0) = hb;
  }
}

// ---------------- global mean pool ----------------
__global__ __launch_bounds__(128) void pool(const float* __restrict__ h_f32,
                                            const int* __restrict__ batch, int N,
                                            float* __restrict__ g_sum) {
  int g = blockIdx.x >> 3, slice = blockIdx.x & 7;
  int c = threadIdx.x;
  int r0 = lower_bound_i(batch, N, g);
  int r1 = lower_bound_i(batch, N, g + 1);
  int len = r1 - r0;
  if (len <= 0) return;
  int per = (len + 7) / 8;
  int s0 = r0 + slice * per;
  int s1 = min(s0 + per, r1);
  if (s0 >= s1) return;
  float acc = 0.f;
  for (int r = s0; r < s1; r++) acc += h_f32[(size_t)r * 128 + c];
  atomicAdd(&g_sum[g * 128 + c], acc);
}

// ---------------- MLP head + output layernorm ----------------
__global__ __launch_bounds__(256) void mlp_head(
    const float* __restrict__ g_sum, const int* __restrict__ batch, int N,
    const float* __restrict__ W1, const float* __restrict__ b1,
    const float* __restrict__ W2, const float* __restrict__ b2,
    const float* __restrict__ og, const float* __restrict__ ob,
    void* __restrict__ outv, const int* __restrict__ flags) {
  __shared__ float gld[128];
  __shared__ float hid[256];
  __shared__ float olds[128];
  __shared__ float red[2];
  int b = blockIdx.x, t = threadIdx.x;
  int r0 = lower_bound_i(batch, N, b);
  int r1 = lower_bound_i(batch, N, b + 1);
  int len = r1 - r0;
  float cntf = (float)(len < 1 ? 1 : len);
  if (t < 128) gld[t] = g_sum[b * 128 + t] / cntf;
  __syncthreads();
  float sacc = b1[t];
  for (int d = 0; d < 128; d++) sacc = fmaf(gld[d], W1[(size_t)t * 128 + d], sacc);
  hid[t] = 0.5f * sacc * (1.f + erff(sacc * 0.70710678118654752f));
  __syncthreads();
  if (t < 128) {
    float o = b2[t];
    for (int k = 0; k < 256; k++) o = fmaf(hid[k], W2[(size_t)t * 256 + k], o);
    olds[t] = o;
  }
  __syncthreads();
  if (t < 64) {
    float a = olds[t], bb = olds[t + 64];
    float s = a + bb, s2 = a * a + bb * bb;
    for (int off = 32; off; off >>= 1) { s += __shfl_down(s, off); s2 += __shfl_down(s2, off); }
    if (t == 0) { red[0] = s * (1.f / 128.f); red[1] = s2 * (1.f / 128.f); }
  }
  __syncthreads();
  if (t < 128) {
    float mu = red[0];
    float var = fmaxf(red[1] - mu * mu, 0.f);
    float rs = rsqrtf(var + EPS);
    float o = (olds[t] - mu) * rs * og[t] + ob[t];
    if (flags[0]) ((__bf16*)outv)[b * 128 + t] = (__bf16)o;
    else          ((float*)outv)[b * 128 + t] = o;
  }
}

extern "C" void kernel_launch(void* const* d_in, const int* in_sizes, int n_in,
                              void* d_out, int out_size, void* d_ws, size_t ws_size,
                              hipStream_t stream) {
  const int D = 128, B = 64;
  const int N = in_sizes[0] / D;      // 50000
  const int E = in_sizes[1] / 2;      // 400000
  const int EN = E + N;

  char* p = (char*)d_ws;
  auto alloc = [&](size_t bytes) {
    char* r = p; p += (bytes + 255) & ~(size_t)255; return (void*)r;
  };
  int* flags     = (int*)alloc(256);
  float* h_f32   = (float*)alloc((size_t)N * 128 * 4);
  __bf16* h_bf   = (__bf16*)alloc((size_t)N * 128 * 2);
  __bf16* comb   = (__bf16*)alloc((size_t)N * 1024 * 2);
  float* logits  = (float*)alloc((size_t)EN * 4 * 4);
  int* deg       = (int*)alloc((size_t)N * 4);
  int* offs      = (int*)alloc((size_t)(N + 1) * 4);
  int* cursor    = (int*)alloc((size_t)N * 4);
  int* csr_src   = (int*)alloc((size_t)EN * 4);
  float* g_sum   = (float*)alloc((size_t)B * 128 * 4);
  int* ei32      = (int*)alloc((size_t)2 * E * 4);
  int* bat32     = (int*)alloc((size_t)N * 4);
  __bf16* w_bf   = (__bf16*)alloc((size_t)2 * 196608 * 2);  // [Wl_all | Wr_all]
  float* params  = (float*)alloc((size_t)71936 * 4);

  // param canonical offsets (floats)
  float* bl_c  = params + 0;       // 1536
  float* br_c  = params + 1536;    // 1536
  float* att_c = params + 3072;    // 1536
  float* cb_c  = params + 4608;    // 384
  float* g_c   = params + 4992;    // 384
  float* b_c   = params + 5376;    // 384
  float* W1_c  = params + 5760;    // 32768
  float* b1_c  = params + 38528;   // 256
  float* W2_c  = params + 38784;   // 32768
  float* b2_c  = params + 71552;   // 128
  float* og_c  = params + 71680;   // 128
  float* ob_c  = params + 71808;   // 128

  detect_dtypes<<<1, 256, 0, stream>>>((const unsigned*)d_in[0], (const unsigned*)d_in[1], flags);

  auto cf = [&](int idx, float* dst, int n) {
    canon_f32<<<(n + 255) / 256, 256, 0, stream>>>(d_in[idx], dst, n, flags);
  };
  cf(0, h_f32, N * 128);
  cf(4, bl_c, 1536);  cf(6, br_c, 1536);  cf(7, att_c, 1536);
  cf(8, cb_c, 384);   cf(9, g_c, 384);    cf(10, b_c, 384);
  cf(11, W1_c, 32768); cf(12, b1_c, 256);
  cf(13, W2_c, 32768); cf(14, b2_c, 128);
  cf(15, og_c, 128);   cf(16, ob_c, 128);

  canon_bf16<<<(196608 + 255) / 256, 256, 0, stream>>>(d_in[3], w_bf, 196608, flags);
  canon_bf16<<<(196608 + 255) / 256, 256, 0, stream>>>(d_in[5], w_bf + 196608, 196608, flags);
  f32_to_bf16<<<(N * 128 + 255) / 256, 256, 0, stream>>>(h_f32, h_bf, N * 128);

  canon_i32<<<(2 * E + 255) / 256, 256, 0, stream>>>(d_in[1], ei32, 2 * E, flags);
  canon_i32<<<(N + 255) / 256, 256, 0, stream>>>(d_in[2], bat32, N, flags);

  hipMemsetAsync(deg, 0, (size_t)N * 4, stream);
  hipMemsetAsync(g_sum, 0, (size_t)B * 128 * 4, stream);

  count_deg<<<(EN + 255) / 256, 256, 0, stream>>>(ei32, E, N, deg);
  scan_offsets<<<1, 1024, 0, stream>>>(deg, offs, cursor, N);
  fill_csr<<<(EN + 255) / 256, 256, 0, stream>>>(ei32, E, N, cursor, csr_src);

  for (int l = 0; l < 3; l++) {
    gemm_xlr<<<dim3((N + 127) / 128, 8), 256, 0, stream>>>(
        h_bf, w_bf + (size_t)l * 65536, w_bf + 196608 + (size_t)l * 65536,
        bl_c + l * 512, br_c + l * 512, comb, N);
    edge_logits<<<(N + 3) / 4, 256, 0, stream>>>(comb, att_c + l * 512, offs, csr_src, logits, N);
    aggregate<<<(N + 3) / 4, 256, 0, stream>>>(comb, logits, offs, csr_src,
        cb_c + l * 128, g_c + l * 128, b_c + l * 128, h_f32, h_bf, N);
  }
  pool<<<B * 8, 128, 0, stream>>>(h_f32, bat32, N, g_sum);
  mlp_head<<<B, 256, 0, stream>>>(g_sum, bat32, N, W1_c, b1_c, W2_c, b2_c, og_c, ob_c, d_out, flags);
}

// Round 3
// 785.574 us; speedup vs baseline: 1.4759x; 1.4759x over previous
//
#include <hip/hip_runtime.h>
#include <hip/hip_bf16.h>

typedef __bf16 bf16x8 __attribute__((ext_vector_type(8)));
typedef float f32x4 __attribute__((ext_vector_type(4)));

#define EPS 1e-5f

static __device__ __forceinline__ int lower_bound_i(const int* __restrict__ arr, int n, int val) {
  int lo = 0, hi = n;
  while (lo < hi) { int mid = (lo + hi) >> 1; if (arr[mid] < val) lo = mid + 1; else hi = mid; }
  return lo;
}

// ---------------- dtype detection ----------------
__global__ void detect_dtypes(const unsigned* __restrict__ xw, const unsigned* __restrict__ eiw,
                              int* __restrict__ flags) {
  __shared__ int s_bf16, s_i64nz;
  int t = threadIdx.x;
  if (t == 0) { s_bf16 = 0; s_i64nz = 0; }
  __syncthreads();
  unsigned w = xw[t * 97];
  unsigned lo = w & 0xFFFFu;
  unsigned e = (lo >> 7) & 0xFF;
  int looks_bf16 = (lo == 0u) || (e >= 0x6A && e <= 0x86);
  atomicAdd(&s_bf16, looks_bf16);
  int k = t * 1031;
  int nz = (eiw[2 * k + 1] != 0u) ? 1 : 0;
  atomicAdd(&s_i64nz, nz);
  __syncthreads();
  if (t == 0) {
    flags[0] = (s_bf16 >= 192) ? 1 : 0;
    flags[1] = (s_i64nz == 0) ? 1 : 0;
  }
}

// ---------------- canonicalization ----------------
__global__ void canon_f32(const void* __restrict__ src, float* __restrict__ dst, int n,
                          const int* __restrict__ flags) {
  int i = blockIdx.x * blockDim.x + threadIdx.x;
  if (i >= n) return;
  if (flags[0]) dst[i] = (float)((const __bf16*)src)[i];
  else          dst[i] = ((const float*)src)[i];
}

__global__ void canon_x(const void* __restrict__ src, float* __restrict__ h_f32,
                        __bf16* __restrict__ h_bf, int n, const int* __restrict__ flags) {
  int i = blockIdx.x * blockDim.x + threadIdx.x;
  if (i >= n) return;
  float v;
  if (flags[0]) v = (float)((const __bf16*)src)[i];
  else          v = ((const float*)src)[i];
  h_f32[i] = v;
  h_bf[i] = (__bf16)v;
}

__global__ void canon_bf16(const void* __restrict__ src, __bf16* __restrict__ dst, int n,
                           const int* __restrict__ flags) {
  int i = blockIdx.x * blockDim.x + threadIdx.x;
  if (i >= n) return;
  if (flags[0]) dst[i] = ((const __bf16*)src)[i];
  else          dst[i] = (__bf16)((const float*)src)[i];
}

__global__ void canon_i32(const void* __restrict__ src, int* __restrict__ dst, int n,
                          const int* __restrict__ flags) {
  int i = blockIdx.x * blockDim.x + threadIdx.x;
  if (i >= n) return;
  if (flags[1]) dst[i] = (int)((const long long*)src)[i];
  else          dst[i] = ((const int*)src)[i];
}

// ---------------- CSR build ----------------
__global__ void count_deg(const int* __restrict__ ei, int E, int N, int* __restrict__ deg) {
  int e = blockIdx.x * blockDim.x + threadIdx.x;
  if (e >= E + N) return;
  int d = (e < E) ? ei[E + e] : (e - E);
  atomicAdd(&deg[d], 1);
}

__global__ void scan_offsets(const int* __restrict__ deg, int* __restrict__ offs,
                             int* __restrict__ cursor, int N) {
  __shared__ int part[1024];
  int t = threadIdx.x;
  int chunk = (N + 1023) / 1024;
  int start = t * chunk, end = min(start + chunk, N);
  int s = 0;
  for (int i = start; i < end; i++) s += deg[i];
  part[t] = s;
  __syncthreads();
  for (int off = 1; off < 1024; off <<= 1) {
    int v = (t >= off) ? part[t - off] : 0;
    __syncthreads();
    part[t] += v;
    __syncthreads();
  }
  int run = (t == 0) ? 0 : part[t - 1];
  for (int i = start; i < end; i++) {
    offs[i] = run; cursor[i] = run; run += deg[i];
  }
  if (end == N && start < N) offs[N] = run;
}

__global__ void fill_csr(const int* __restrict__ ei, int E, int N,
                         int* __restrict__ cursor, int* __restrict__ csr_src) {
  int e = blockIdx.x * blockDim.x + threadIdx.x;
  if (e >= E + N) return;
  int s, d;
  if (e < E) { s = ei[e]; d = ei[E + e]; } else { s = e - E; d = e - E; }
  int pos = atomicAdd(&cursor[d], 1);
  csr_src[pos] = s;
}

// ---------------- GEMM: comb[n, 0:512]=xl, [512:1024]=xr ----------------
__global__ __launch_bounds__(256) void gemm_xlr(
    const __bf16* __restrict__ A, const __bf16* __restrict__ Wl,
    const __bf16* __restrict__ Wr, const float* __restrict__ bl,
    const float* __restrict__ br, __bf16* __restrict__ out, int Nrows) {
  __shared__ __bf16 As[128][72];
  __shared__ __bf16 Bs[128][72];
  const int jb = blockIdx.y;
  const __bf16* Wbase = (jb < 4) ? (Wl + (size_t)jb * 128 * 128) : (Wr + (size_t)(jb - 4) * 128 * 128);
  const float* biasbase = (jb < 4) ? (bl + jb * 128) : (br + (jb - 4) * 128);
  const int row0 = blockIdx.x * 128;
  const int tid = threadIdx.x;
  const int lane = tid & 63, wave = tid >> 6;
  const int wm = wave >> 1, wn = wave & 1;

  f32x4 zero4 = {0.f, 0.f, 0.f, 0.f};
  f32x4 acc[4][4];
#pragma unroll
  for (int mi = 0; mi < 4; mi++)
#pragma unroll
    for (int ni = 0; ni < 4; ni++) acc[mi][ni] = zero4;

  for (int kc = 0; kc < 2; kc++) {
    __syncthreads();
#pragma unroll
    for (int p = 0; p < 4; p++) {
      int r = (tid >> 3) + p * 32;
      int cg = (tid & 7) * 8;
      int gr = row0 + r;
      bf16x8 av;
      if (gr < Nrows) av = *(const bf16x8*)(A + (size_t)gr * 128 + kc * 64 + cg);
      else {
#pragma unroll
        for (int j = 0; j < 8; j++) av[j] = (__bf16)0.0f;
      }
      *(bf16x8*)(&As[r][cg]) = av;
      bf16x8 bv = *(const bf16x8*)(Wbase + (size_t)r * 128 + kc * 64 + cg);
      *(bf16x8*)(&Bs[r][cg]) = bv;
    }
    __syncthreads();
#pragma unroll
    for (int s = 0; s < 2; s++) {
      bf16x8 af[4], bfr[4];
      int kofs = s * 32 + ((lane >> 4) * 8);
#pragma unroll
      for (int i = 0; i < 4; i++) {
        af[i]  = *(const bf16x8*)(&As[wm * 64 + i * 16 + (lane & 15)][kofs]);
        bfr[i] = *(const bf16x8*)(&Bs[wn * 64 + i * 16 + (lane & 15)][kofs]);
      }
#pragma unroll
      for (int mi = 0; mi < 4; mi++)
#pragma unroll
        for (int ni = 0; ni < 4; ni++)
          acc[mi][ni] = __builtin_amdgcn_mfma_f32_16x16x32_bf16(af[mi], bfr[ni], acc[mi][ni], 0, 0, 0);
    }
  }
#pragma unroll
  for (int mi = 0; mi < 4; mi++) {
#pragma unroll
    for (int ni = 0; ni < 4; ni++) {
      int col_l = wn * 64 + ni * 16 + (lane & 15);
      int gj = jb * 128 + col_l;
      float bias = biasbase[col_l];
#pragma unroll
      for (int r = 0; r < 4; r++) {
        int row_l = wm * 64 + mi * 16 + (lane >> 4) * 4 + r;
        int gr = row0 + row_l;
        if (gr < Nrows) out[(size_t)gr * 1024 + gj] = (__bf16)(acc[mi][ni][r] + bias);
      }
    }
  }
}

// ---------------- fused GAT layer: single gather + online softmax ----------------
// per edge: gather xl row once; logit from registers; online-softmax rescale.
__global__ __launch_bounds__(256) void gat_fused(
    const __bf16* __restrict__ comb, const float* __restrict__ att,
    const int* __restrict__ offs, const int* __restrict__ csr_src,
    const float* __restrict__ conv_bias, const float* __restrict__ gamma,
    const float* __restrict__ beta, float* __restrict__ h_f32,
    __bf16* __restrict__ h_bf, int N) {
  int wid = blockIdx.x * 4 + (threadIdx.x >> 6);
  int lane = threadIdx.x & 63;
  if (wid >= N) return;
  int n = wid;
  float xr[8], at[8];
  bf16x8 xrv = *(const bf16x8*)(comb + (size_t)n * 1024 + 512 + lane * 8);
  float4 a0 = *(const float4*)(att + lane * 8);
  float4 a1 = *(const float4*)(att + lane * 8 + 4);
  at[0] = a0.x; at[1] = a0.y; at[2] = a0.z; at[3] = a0.w;
  at[4] = a1.x; at[5] = a1.y; at[6] = a1.z; at[7] = a1.w;
#pragma unroll
  for (int j = 0; j < 8; j++) xr[j] = (float)xrv[j];
  int off0 = offs[n], off1 = offs[n + 1];

  float m = -1e30f, l = 0.f;
  float acc[8];
#pragma unroll
  for (int j = 0; j < 8; j++) acc[j] = 0.f;

  for (int pos = off0; pos < off1; pos++) {
    int src = csr_src[pos];
    bf16x8 xlv = *(const bf16x8*)(comb + (size_t)src * 1024 + lane * 8);
    float xlf[8];
    float t = 0.f;
#pragma unroll
    for (int j = 0; j < 8; j++) {
      xlf[j] = (float)xlv[j];
      float z = xlf[j] + xr[j];
      float lr = z > 0.f ? z : 0.2f * z;
      t = fmaf(lr, at[j], t);
    }
    t += __shfl_xor(t, 1);
    t += __shfl_xor(t, 2);
    t += __shfl_xor(t, 4);
    t += __shfl_xor(t, 8);
    // online softmax update (per head: all 16 lanes of the group carry same m,l)
    float mn = fmaxf(m, t);
    float c = __expf(m - mn);   // m=-1e30 first iter -> c=0
    float p = __expf(t - mn);
    l = fmaf(l, c, p);
#pragma unroll
    for (int j = 0; j < 8; j++) acc[j] = fmaf(acc[j], c, p * xlf[j]);
    m = mn;
  }
  float invl = 1.0f / fmaxf(l, 1e-30f);
#pragma unroll
  for (int j = 0; j < 8; j++) acc[j] *= invl;
  // mean over heads
#pragma unroll
  for (int j = 0; j < 8; j++) {
    acc[j] += __shfl_xor(acc[j], 16);
    acc[j] += __shfl_xor(acc[j], 32);
  }
  int c0 = (lane & 15) * 8;
  float v[8];
  float s = 0.f, s2 = 0.f;
#pragma unroll
  for (int j = 0; j < 8; j++) {
    v[j] = acc[j] * 0.25f + conv_bias[c0 + j];
    s += v[j]; s2 += v[j] * v[j];
  }
  s  += __shfl_xor(s, 1);  s2 += __shfl_xor(s2, 1);
  s  += __shfl_xor(s, 2);  s2 += __shfl_xor(s2, 2);
  s  += __shfl_xor(s, 4);  s2 += __shfl_xor(s2, 4);
  s  += __shfl_xor(s, 8);  s2 += __shfl_xor(s2, 8);
  float mu = s * (1.f / 128.f);
  float var = fmaxf(s2 * (1.f / 128.f) - mu * mu, 0.f);
  float rs = rsqrtf(var + EPS);
  if (lane < 16) {
    float4 o0, o1;
    bf16x8 hb;
    float hn[8];
#pragma unroll
    for (int j = 0; j < 8; j++) {
      float o = (v[j] - mu) * rs * gamma[c0 + j] + beta[c0 + j];
      o = o > 0.f ? o : 0.f;
      hn[j] = h_f32[(size_t)n * 128 + c0 + j] + o;
      hb[j] = (__bf16)hn[j];
    }
    o0.x = hn[0]; o0.y = hn[1]; o0.z = hn[2]; o0.w = hn[3];
    o1.x = hn[4]; o1.y = hn[5]; o1.z = hn[6]; o1.w = hn[7];
    *(float4*)(h_f32 + (size_t)n * 128 + c0) = o0;
    *(float4*)(h_f32 + (size_t)n * 128 + c0 + 4) = o1;
    *(bf16x8*)(h_bf + (size_t)n * 128 + c0) = hb;
  }
}

// ---------------- global mean pool ----------------
__global__ __launch_bounds__(128) void pool(const float* __restrict__ h_f32,
                                            const int* __restrict__ batch, int N,
                                            float* __restrict__ g_sum) {
  int g = blockIdx.x >> 3, slice = blockIdx.x & 7;
  int c = threadIdx.x;
  int r0 = lower_bound_i(batch, N, g);
  int r1 = lower_bound_i(batch, N, g + 1);
  int len = r1 - r0;
  if (len <= 0) return;
  int per = (len + 7) / 8;
  int s0 = r0 + slice * per;
  int s1 = min(s0 + per, r1);
  if (s0 >= s1) return;
  float acc = 0.f;
  for (int r = s0; r < s1; r++) acc += h_f32[(size_t)r * 128 + c];
  atomicAdd(&g_sum[g * 128 + c], acc);
}

// ---------------- MLP head + output layernorm ----------------
__global__ __launch_bounds__(256) void mlp_head(
    const float* __restrict__ g_sum, const int* __restrict__ batch, int N,
    const float* __restrict__ W1, const float* __restrict__ b1,
    const float* __restrict__ W2, const float* __restrict__ b2,
    const float* __restrict__ og, const float* __restrict__ ob,
    void* __restrict__ outv, const int* __restrict__ flags) {
  __shared__ float gld[128];
  __shared__ float hid[256];
  __shared__ float olds[128];
  __shared__ float red[2];
  int b = blockIdx.x, t = threadIdx.x;
  int r0 = lower_bound_i(batch, N, b);
  int r1 = lower_bound_i(batch, N, b + 1);
  int len = r1 - r0;
  float cntf = (float)(len < 1 ? 1 : len);
  if (t < 128) gld[t] = g_sum[b * 128 + t] / cntf;
  __syncthreads();
  float sacc = b1[t];
  for (int d = 0; d < 128; d++) sacc = fmaf(gld[d], W1[(size_t)t * 128 + d], sacc);
  hid[t] = 0.5f * sacc * (1.f + erff(sacc * 0.70710678118654752f));
  __syncthreads();
  if (t < 128) {
    float o = b2[t];
    for (int k = 0; k < 256; k++) o = fmaf(hid[k], W2[(size_t)t * 256 + k], o);
    olds[t] = o;
  }
  __syncthreads();
  if (t < 64) {
    float a = olds[t], bb = olds[t + 64];
    float s = a + bb, s2 = a * a + bb * bb;
    for (int off = 32; off; off >>= 1) { s += __shfl_down(s, off); s2 += __shfl_down(s2, off); }
    if (t == 0) { red[0] = s * (1.f / 128.f); red[1] = s2 * (1.f / 128.f); }
  }
  __syncthreads();
  if (t < 128) {
    float mu = red[0];
    float var = fmaxf(red[1] - mu * mu, 0.f);
    float rs = rsqrtf(var + EPS);
    float o = (olds[t] - mu) * rs * og[t] + ob[t];
    if (flags[0]) ((__bf16*)outv)[b * 128 + t] = (__bf16)o;
    else          ((float*)outv)[b * 128 + t] = o;
  }
}

extern "C" void kernel_launch(void* const* d_in, const int* in_sizes, int n_in,
                              void* d_out, int out_size, void* d_ws, size_t ws_size,
                              hipStream_t stream) {
  const int D = 128, B = 64;
  const int N = in_sizes[0] / D;
  const int E = in_sizes[1] / 2;
  const int EN = E + N;

  char* p = (char*)d_ws;
  auto alloc = [&](size_t bytes) {
    char* r = p; p += (bytes + 255) & ~(size_t)255; return (void*)r;
  };
  int* flags     = (int*)alloc(256);
  float* h_f32   = (float*)alloc((size_t)N * 128 * 4);
  __bf16* h_bf   = (__bf16*)alloc((size_t)N * 128 * 2);
  __bf16* comb   = (__bf16*)alloc((size_t)N * 1024 * 2);
  int* deg       = (int*)alloc((size_t)N * 4);
  int* offs      = (int*)alloc((size_t)(N + 1) * 4);
  int* cursor    = (int*)alloc((size_t)N * 4);
  int* csr_src   = (int*)alloc((size_t)EN * 4);
  float* g_sum   = (float*)alloc((size_t)B * 128 * 4);
  int* ei32      = (int*)alloc((size_t)2 * E * 4);
  int* bat32     = (int*)alloc((size_t)N * 4);
  __bf16* w_bf   = (__bf16*)alloc((size_t)2 * 196608 * 2);
  float* params  = (float*)alloc((size_t)71936 * 4);

  float* bl_c  = params + 0;
  float* br_c  = params + 1536;
  float* att_c = params + 3072;
  float* cb_c  = params + 4608;
  float* g_c   = params + 4992;
  float* b_c   = params + 5376;
  float* W1_c  = params + 5760;
  float* b1_c  = params + 38528;
  float* W2_c  = params + 38784;
  float* b2_c  = params + 71552;
  float* og_c  = params + 71680;
  float* ob_c  = params + 71808;

  detect_dtypes<<<1, 256, 0, stream>>>((const unsigned*)d_in[0], (const unsigned*)d_in[1], flags);

  auto cf = [&](int idx, float* dst, int n) {
    canon_f32<<<(n + 255) / 256, 256, 0, stream>>>(d_in[idx], dst, n, flags);
  };
  canon_x<<<(N * 128 + 255) / 256, 256, 0, stream>>>(d_in[0], h_f32, h_bf, N * 128, flags);
  cf(4, bl_c, 1536);  cf(6, br_c, 1536);  cf(7, att_c, 1536);
  cf(8, cb_c, 384);   cf(9, g_c, 384);    cf(10, b_c, 384);
  cf(11, W1_c, 32768); cf(12, b1_c, 256);
  cf(13, W2_c, 32768); cf(14, b2_c, 128);
  cf(15, og_c, 128);   cf(16, ob_c, 128);

  canon_bf16<<<(196608 + 255) / 256, 256, 0, stream>>>(d_in[3], w_bf, 196608, flags);
  canon_bf16<<<(196608 + 255) / 256, 256, 0, stream>>>(d_in[5], w_bf + 196608, 196608, flags);

  canon_i32<<<(2 * E + 255) / 256, 256, 0, stream>>>(d_in[1], ei32, 2 * E, flags);
  canon_i32<<<(N + 255) / 256, 256, 0, stream>>>(d_in[2], bat32, N, flags);

  hipMemsetAsync(deg, 0, (size_t)N * 4, stream);
  hipMemsetAsync(g_sum, 0, (size_t)B * 128 * 4, stream);

  count_deg<<<(EN + 255) / 256, 256, 0, stream>>>(ei32, E, N, deg);
  scan_offsets<<<1, 1024, 0, stream>>>(deg, offs, cursor, N);
  fill_csr<<<(EN + 255) / 256, 256, 0, stream>>>(ei32, E, N, cursor, csr_src);

  for (int l = 0; l < 3; l++) {
    gemm_xlr<<<dim3((N + 127) / 128, 8), 256, 0, stream>>>(
        h_bf, w_bf + (size_t)l * 65536, w_bf + 196608 + (size_t)l * 65536,
        bl_c + l * 512, br_c + l * 512, comb, N);
    gat_fused<<<(N + 3) / 4, 256, 0, stream>>>(comb, att_c + l * 512, offs, csr_src,
        cb_c + l * 128, g_c + l * 128, b_c + l * 128, h_f32, h_bf, N);
  }
  pool<<<B * 8, 128, 0, stream>>>(h_f32, bat32, N, g_sum);
  mlp_head<<<B, 256, 0, stream>>>(g_sum, bat32, N, W1_c, b1_c, W2_c, b2_c, og_c, ob_c, d_out, flags);
}

// Round 4
// 687.914 us; speedup vs baseline: 1.6854x; 1.1420x over previous
//
#include <hip/hip_runtime.h>
#include <hip/hip_bf16.h>

typedef __bf16 bf16x8 __attribute__((ext_vector_type(8)));
typedef float f32x4 __attribute__((ext_vector_type(4)));

#define EPS 1e-5f

static __device__ __forceinline__ int lower_bound_i(const int* __restrict__ arr, int n, int val) {
  int lo = 0, hi = n;
  while (lo < hi) { int mid = (lo + hi) >> 1; if (arr[mid] < val) lo = mid + 1; else hi = mid; }
  return lo;
}

// ---------------- dtype detection ----------------
__global__ void detect_dtypes(const unsigned* __restrict__ xw, const unsigned* __restrict__ eiw,
                              int* __restrict__ flags) {
  __shared__ int s_bf16, s_i64nz;
  int t = threadIdx.x;
  if (t == 0) { s_bf16 = 0; s_i64nz = 0; }
  __syncthreads();
  unsigned w = xw[t * 97];
  unsigned lo = w & 0xFFFFu;
  unsigned e = (lo >> 7) & 0xFF;
  int looks_bf16 = (lo == 0u) || (e >= 0x6A && e <= 0x86);
  atomicAdd(&s_bf16, looks_bf16);
  int k = t * 1031;
  int nz = (eiw[2 * k + 1] != 0u) ? 1 : 0;
  atomicAdd(&s_i64nz, nz);
  __syncthreads();
  if (t == 0) {
    flags[0] = (s_bf16 >= 192) ? 1 : 0;
    flags[1] = (s_i64nz == 0) ? 1 : 0;
  }
}

// ---------------- canonicalization ----------------
__global__ void canon_f32(const void* __restrict__ src, float* __restrict__ dst, int n,
                          const int* __restrict__ flags) {
  int i = blockIdx.x * blockDim.x + threadIdx.x;
  if (i >= n) return;
  if (flags[0]) dst[i] = (float)((const __bf16*)src)[i];
  else          dst[i] = ((const float*)src)[i];
}

__global__ void canon_x(const void* __restrict__ src, float* __restrict__ h_f32,
                        __bf16* __restrict__ h_bf, int n, const int* __restrict__ flags) {
  int i = blockIdx.x * blockDim.x + threadIdx.x;
  if (i >= n) return;
  float v;
  if (flags[0]) v = (float)((const __bf16*)src)[i];
  else          v = ((const float*)src)[i];
  h_f32[i] = v;
  h_bf[i] = (__bf16)v;
}

__global__ void canon_bf16(const void* __restrict__ src, __bf16* __restrict__ dst, int n,
                           const int* __restrict__ flags) {
  int i = blockIdx.x * blockDim.x + threadIdx.x;
  if (i >= n) return;
  if (flags[0]) dst[i] = ((const __bf16*)src)[i];
  else          dst[i] = (__bf16)((const float*)src)[i];
}

__global__ void canon_i32(const void* __restrict__ src, int* __restrict__ dst, int n,
                          const int* __restrict__ flags) {
  int i = blockIdx.x * blockDim.x + threadIdx.x;
  if (i >= n) return;
  if (flags[1]) dst[i] = (int)((const long long*)src)[i];
  else          dst[i] = ((const int*)src)[i];
}

// ---------------- CSR build ----------------
__global__ void count_deg(const int* __restrict__ ei, int E, int N, int* __restrict__ deg) {
  int e = blockIdx.x * blockDim.x + threadIdx.x;
  if (e >= E + N) return;
  int d = (e < E) ? ei[E + e] : (e - E);
  atomicAdd(&deg[d], 1);
}

// --- device-wide exclusive scan over deg[0..N) in three tiny kernels ---
__global__ __launch_bounds__(256) void block_sums(const int* __restrict__ deg,
                                                  int* __restrict__ bsum, int N) {
  __shared__ int sh[256];
  int i = blockIdx.x * 256 + threadIdx.x;
  int t = threadIdx.x;
  sh[t] = (i < N) ? deg[i] : 0;
  __syncthreads();
  for (int off = 128; off > 0; off >>= 1) {
    if (t < off) sh[t] += sh[t + off];
    __syncthreads();
  }
  if (t == 0) bsum[blockIdx.x] = sh[0];
}

__global__ __launch_bounds__(256) void scan_bsums(const int* __restrict__ bsum,
                                                  int* __restrict__ bpref, int nblocks,
                                                  int* __restrict__ offs, int N) {
  __shared__ int sh[256];
  int t = threadIdx.x;
  int carry = 0;
  for (int base = 0; base < nblocks; base += 256) {
    int idx = base + t;
    int v = (idx < nblocks) ? bsum[idx] : 0;
    sh[t] = v;
    __syncthreads();
    for (int off = 1; off < 256; off <<= 1) {
      int u = (t >= off) ? sh[t - off] : 0;
      __syncthreads();
      sh[t] += u;
      __syncthreads();
    }
    if (idx < nblocks) bpref[idx] = carry + sh[t] - v;
    carry += sh[255];
    __syncthreads();
  }
  if (t == 0) offs[N] = carry;
}

__global__ __launch_bounds__(256) void write_offs(const int* __restrict__ deg,
                                                  const int* __restrict__ bpref,
                                                  int* __restrict__ offs,
                                                  int* __restrict__ cursor, int N) {
  __shared__ int sh[256];
  int i = blockIdx.x * 256 + threadIdx.x;
  int t = threadIdx.x;
  int v = (i < N) ? deg[i] : 0;
  sh[t] = v;
  __syncthreads();
  for (int off = 1; off < 256; off <<= 1) {
    int u = (t >= off) ? sh[t - off] : 0;
    __syncthreads();
    sh[t] += u;
    __syncthreads();
  }
  if (i < N) {
    int ex = bpref[blockIdx.x] + sh[t] - v;
    offs[i] = ex;
    cursor[i] = ex;
  }
}

__global__ void fill_csr(const int* __restrict__ ei, int E, int N,
                         int* __restrict__ cursor, int* __restrict__ csr_src) {
  int e = blockIdx.x * blockDim.x + threadIdx.x;
  if (e >= E + N) return;
  int s, d;
  if (e < E) { s = ei[e]; d = ei[E + e]; } else { s = e - E; d = e - E; }
  int pos = atomicAdd(&cursor[d], 1);
  csr_src[pos] = s;
}

// ---------------- GEMM: comb[n, 0:512]=xl, [512:1024]=xr ----------------
__global__ __launch_bounds__(256) void gemm_xlr(
    const __bf16* __restrict__ A, const __bf16* __restrict__ Wl,
    const __bf16* __restrict__ Wr, const float* __restrict__ bl,
    const float* __restrict__ br, __bf16* __restrict__ out, int Nrows) {
  __shared__ __bf16 As[128][72];
  __shared__ __bf16 Bs[128][72];
  const int jb = blockIdx.y;
  const __bf16* Wbase = (jb < 4) ? (Wl + (size_t)jb * 128 * 128) : (Wr + (size_t)(jb - 4) * 128 * 128);
  const float* biasbase = (jb < 4) ? (bl + jb * 128) : (br + (jb - 4) * 128);
  const int row0 = blockIdx.x * 128;
  const int tid = threadIdx.x;
  const int lane = tid & 63, wave = tid >> 6;
  const int wm = wave >> 1, wn = wave & 1;

  f32x4 zero4 = {0.f, 0.f, 0.f, 0.f};
  f32x4 acc[4][4];
#pragma unroll
  for (int mi = 0; mi < 4; mi++)
#pragma unroll
    for (int ni = 0; ni < 4; ni++) acc[mi][ni] = zero4;

  for (int kc = 0; kc < 2; kc++) {
    __syncthreads();
#pragma unroll
    for (int p = 0; p < 4; p++) {
      int r = (tid >> 3) + p * 32;
      int cg = (tid & 7) * 8;
      int gr = row0 + r;
      bf16x8 av;
      if (gr < Nrows) av = *(const bf16x8*)(A + (size_t)gr * 128 + kc * 64 + cg);
      else {
#pragma unroll
        for (int j = 0; j < 8; j++) av[j] = (__bf16)0.0f;
      }
      *(bf16x8*)(&As[r][cg]) = av;
      bf16x8 bv = *(const bf16x8*)(Wbase + (size_t)r * 128 + kc * 64 + cg);
      *(bf16x8*)(&Bs[r][cg]) = bv;
    }
    __syncthreads();
#pragma unroll
    for (int s = 0; s < 2; s++) {
      bf16x8 af[4], bfr[4];
      int kofs = s * 32 + ((lane >> 4) * 8);
#pragma unroll
      for (int i = 0; i < 4; i++) {
        af[i]  = *(const bf16x8*)(&As[wm * 64 + i * 16 + (lane & 15)][kofs]);
        bfr[i] = *(const bf16x8*)(&Bs[wn * 64 + i * 16 + (lane & 15)][kofs]);
      }
#pragma unroll
      for (int mi = 0; mi < 4; mi++)
#pragma unroll
        for (int ni = 0; ni < 4; ni++)
          acc[mi][ni] = __builtin_amdgcn_mfma_f32_16x16x32_bf16(af[mi], bfr[ni], acc[mi][ni], 0, 0, 0);
    }
  }
#pragma unroll
  for (int mi = 0; mi < 4; mi++) {
#pragma unroll
    for (int ni = 0; ni < 4; ni++) {
      int col_l = wn * 64 + ni * 16 + (lane & 15);
      int gj = jb * 128 + col_l;
      float bias = biasbase[col_l];
#pragma unroll
      for (int r = 0; r < 4; r++) {
        int row_l = wm * 64 + mi * 16 + (lane >> 4) * 4 + r;
        int gr = row0 + row_l;
        if (gr < Nrows) out[(size_t)gr * 1024 + gj] = (__bf16)(acc[mi][ni][r] + bias);
      }
    }
  }
}

// ---------------- fused GAT layer: single gather + online softmax ----------------
__global__ __launch_bounds__(256) void gat_fused(
    const __bf16* __restrict__ comb, const float* __restrict__ att,
    const int* __restrict__ offs, const int* __restrict__ csr_src,
    const float* __restrict__ conv_bias, const float* __restrict__ gamma,
    const float* __restrict__ beta, float* __restrict__ h_f32,
    __bf16* __restrict__ h_bf, int N) {
  int wid = blockIdx.x * 4 + (threadIdx.x >> 6);
  int lane = threadIdx.x & 63;
  if (wid >= N) return;
  int n = wid;
  float xr[8], at[8];
  bf16x8 xrv = *(const bf16x8*)(comb + (size_t)n * 1024 + 512 + lane * 8);
  float4 a0 = *(const float4*)(att + lane * 8);
  float4 a1 = *(const float4*)(att + lane * 8 + 4);
  at[0] = a0.x; at[1] = a0.y; at[2] = a0.z; at[3] = a0.w;
  at[4] = a1.x; at[5] = a1.y; at[6] = a1.z; at[7] = a1.w;
#pragma unroll
  for (int j = 0; j < 8; j++) xr[j] = (float)xrv[j];
  int off0 = offs[n], off1 = offs[n + 1];

  float m = -1e30f, l = 0.f;
  float acc[8];
#pragma unroll
  for (int j = 0; j < 8; j++) acc[j] = 0.f;

  for (int pos = off0; pos < off1; pos++) {
    int src = csr_src[pos];
    bf16x8 xlv = *(const bf16x8*)(comb + (size_t)src * 1024 + lane * 8);
    float xlf[8];
    float t = 0.f;
#pragma unroll
    for (int j = 0; j < 8; j++) {
      xlf[j] = (float)xlv[j];
      float z = xlf[j] + xr[j];
      float lr = z > 0.f ? z : 0.2f * z;
      t = fmaf(lr, at[j], t);
    }
    t += __shfl_xor(t, 1);
    t += __shfl_xor(t, 2);
    t += __shfl_xor(t, 4);
    t += __shfl_xor(t, 8);
    float mn = fmaxf(m, t);
    float c = __expf(m - mn);
    float p = __expf(t - mn);
    l = fmaf(l, c, p);
#pragma unroll
    for (int j = 0; j < 8; j++) acc[j] = fmaf(acc[j], c, p * xlf[j]);
    m = mn;
  }
  float invl = 1.0f / fmaxf(l, 1e-30f);
#pragma unroll
  for (int j = 0; j < 8; j++) acc[j] *= invl;
#pragma unroll
  for (int j = 0; j < 8; j++) {
    acc[j] += __shfl_xor(acc[j], 16);
    acc[j] += __shfl_xor(acc[j], 32);
  }
  int c0 = (lane & 15) * 8;
  float v[8];
  float s = 0.f, s2 = 0.f;
#pragma unroll
  for (int j = 0; j < 8; j++) {
    v[j] = acc[j] * 0.25f + conv_bias[c0 + j];
    s += v[j]; s2 += v[j] * v[j];
  }
  s  += __shfl_xor(s, 1);  s2 += __shfl_xor(s2, 1);
  s  += __shfl_xor(s, 2);  s2 += __shfl_xor(s2, 2);
  s  += __shfl_xor(s, 4);  s2 += __shfl_xor(s2, 4);
  s  += __shfl_xor(s, 8);  s2 += __shfl_xor(s2, 8);
  float mu = s * (1.f / 128.f);
  float var = fmaxf(s2 * (1.f / 128.f) - mu * mu, 0.f);
  float rs = rsqrtf(var + EPS);
  if (lane < 16) {
    float4 o0, o1;
    bf16x8 hb;
    float hn[8];
#pragma unroll
    for (int j = 0; j < 8; j++) {
      float o = (v[j] - mu) * rs * gamma[c0 + j] + beta[c0 + j];
      o = o > 0.f ? o : 0.f;
      hn[j] = h_f32[(size_t)n * 128 + c0 + j] + o;
      hb[j] = (__bf16)hn[j];
    }
    o0.x = hn[0]; o0.y = hn[1]; o0.z = hn[2]; o0.w = hn[3];
    o1.x = hn[4]; o1.y = hn[5]; o1.z = hn[6]; o1.w = hn[7];
    *(float4*)(h_f32 + (size_t)n * 128 + c0) = o0;
    *(float4*)(h_f32 + (size_t)n * 128 + c0 + 4) = o1;
    *(bf16x8*)(h_bf + (size_t)n * 128 + c0) = hb;
  }
}

// ---------------- global mean pool ----------------
__global__ __launch_bounds__(128) void pool(const float* __restrict__ h_f32,
                                            const int* __restrict__ batch, int N,
                                            float* __restrict__ g_sum) {
  int g = blockIdx.x >> 3, slice = blockIdx.x & 7;
  int c = threadIdx.x;
  int r0 = lower_bound_i(batch, N, g);
  int r1 = lower_bound_i(batch, N, g + 1);
  int len = r1 - r0;
  if (len <= 0) return;
  int per = (len + 7) / 8;
  int s0 = r0 + slice * per;
  int s1 = min(s0 + per, r1);
  if (s0 >= s1) return;
  float acc = 0.f;
  for (int r = s0; r < s1; r++) acc += h_f32[(size_t)r * 128 + c];
  atomicAdd(&g_sum[g * 128 + c], acc);
}

// ---------------- MLP head + output layernorm ----------------
__global__ __launch_bounds__(256) void mlp_head(
    const float* __restrict__ g_sum, const int* __restrict__ batch, int N,
    const float* __restrict__ W1, const float* __restrict__ b1,
    const float* __restrict__ W2, const float* __restrict__ b2,
    const float* __restrict__ og, const float* __restrict__ ob,
    void* __restrict__ outv, const int* __restrict__ flags) {
  __shared__ float gld[128];
  __shared__ float hid[256];
  __shared__ float olds[128];
  __shared__ float red[2];
  int b = blockIdx.x, t = threadIdx.x;
  int r0 = lower_bound_i(batch, N, b);
  int r1 = lower_bound_i(batch, N, b + 1);
  int len = r1 - r0;
  float cntf = (float)(len < 1 ? 1 : len);
  if (t < 128) gld[t] = g_sum[b * 128 + t] / cntf;
  __syncthreads();
  float sacc = b1[t];
  for (int d = 0; d < 128; d++) sacc = fmaf(gld[d], W1[(size_t)t * 128 + d], sacc);
  hid[t] = 0.5f * sacc * (1.f + erff(sacc * 0.70710678118654752f));
  __syncthreads();
  if (t < 128) {
    float o = b2[t];
    for (int k = 0; k < 256; k++) o = fmaf(hid[k], W2[(size_t)t * 256 + k], o);
    olds[t] = o;
  }
  __syncthreads();
  if (t < 64) {
    float a = olds[t], bb = olds[t + 64];
    float s = a + bb, s2 = a * a + bb * bb;
    for (int off = 32; off; off >>= 1) { s += __shfl_down(s, off); s2 += __shfl_down(s2, off); }
    if (t == 0) { red[0] = s * (1.f / 128.f); red[1] = s2 * (1.f / 128.f); }
  }
  __syncthreads();
  if (t < 128) {
    float mu = red[0];
    float var = fmaxf(red[1] - mu * mu, 0.f);
    float rs = rsqrtf(var + EPS);
    float o = (olds[t] - mu) * rs * og[t] + ob[t];
    if (flags[0]) ((__bf16*)outv)[b * 128 + t] = (__bf16)o;
    else          ((float*)outv)[b * 128 + t] = o;
  }
}

extern "C" void kernel_launch(void* const* d_in, const int* in_sizes, int n_in,
                              void* d_out, int out_size, void* d_ws, size_t ws_size,
                              hipStream_t stream) {
  const int D = 128, B = 64;
  const int N = in_sizes[0] / D;
  const int E = in_sizes[1] / 2;
  const int EN = E + N;
  const int nsb = (N + 255) / 256;

  char* p = (char*)d_ws;
  auto alloc = [&](size_t bytes) {
    char* r = p; p += (bytes + 255) & ~(size_t)255; return (void*)r;
  };
  int* flags     = (int*)alloc(256);
  float* h_f32   = (float*)alloc((size_t)N * 128 * 4);
  __bf16* h_bf   = (__bf16*)alloc((size_t)N * 128 * 2);
  __bf16* comb   = (__bf16*)alloc((size_t)N * 1024 * 2);
  int* deg       = (int*)alloc((size_t)N * 4);
  int* offs      = (int*)alloc((size_t)(N + 1) * 4);
  int* cursor    = (int*)alloc((size_t)N * 4);
  int* csr_src   = (int*)alloc((size_t)EN * 4);
  float* g_sum   = (float*)alloc((size_t)B * 128 * 4);
  int* ei32      = (int*)alloc((size_t)2 * E * 4);
  int* bat32     = (int*)alloc((size_t)N * 4);
  int* bsum      = (int*)alloc((size_t)nsb * 4);
  int* bpref     = (int*)alloc((size_t)nsb * 4);
  __bf16* w_bf   = (__bf16*)alloc((size_t)2 * 196608 * 2);
  float* params  = (float*)alloc((size_t)71936 * 4);

  float* bl_c  = params + 0;
  float* br_c  = params + 1536;
  float* att_c = params + 3072;
  float* cb_c  = params + 4608;
  float* g_c   = params + 4992;
  float* b_c   = params + 5376;
  float* W1_c  = params + 5760;
  float* b1_c  = params + 38528;
  float* W2_c  = params + 38784;
  float* b2_c  = params + 71552;
  float* og_c  = params + 71680;
  float* ob_c  = params + 71808;

  detect_dtypes<<<1, 256, 0, stream>>>((const unsigned*)d_in[0], (const unsigned*)d_in[1], flags);

  auto cf = [&](int idx, float* dst, int n) {
    canon_f32<<<(n + 255) / 256, 256, 0, stream>>>(d_in[idx], dst, n, flags);
  };
  canon_x<<<(N * 128 + 255) / 256, 256, 0, stream>>>(d_in[0], h_f32, h_bf, N * 128, flags);
  cf(4, bl_c, 1536);  cf(6, br_c, 1536);  cf(7, att_c, 1536);
  cf(8, cb_c, 384);   cf(9, g_c, 384);    cf(10, b_c, 384);
  cf(11, W1_c, 32768); cf(12, b1_c, 256);
  cf(13, W2_c, 32768); cf(14, b2_c, 128);
  cf(15, og_c, 128);   cf(16, ob_c, 128);

  canon_bf16<<<(196608 + 255) / 256, 256, 0, stream>>>(d_in[3], w_bf, 196608, flags);
  canon_bf16<<<(196608 + 255) / 256, 256, 0, stream>>>(d_in[5], w_bf + 196608, 196608, flags);

  canon_i32<<<(2 * E + 255) / 256, 256, 0, stream>>>(d_in[1], ei32, 2 * E, flags);
  canon_i32<<<(N + 255) / 256, 256, 0, stream>>>(d_in[2], bat32, N, flags);

  hipMemsetAsync(deg, 0, (size_t)N * 4, stream);
  hipMemsetAsync(g_sum, 0, (size_t)B * 128 * 4, stream);

  count_deg<<<(EN + 255) / 256, 256, 0, stream>>>(ei32, E, N, deg);
  block_sums<<<nsb, 256, 0, stream>>>(deg, bsum, N);
  scan_bsums<<<1, 256, 0, stream>>>(bsum, bpref, nsb, offs, N);
  write_offs<<<nsb, 256, 0, stream>>>(deg, bpref, offs, cursor, N);
  fill_csr<<<(EN + 255) / 256, 256, 0, stream>>>(ei32, E, N, cursor, csr_src);

  for (int l = 0; l < 3; l++) {
    gemm_xlr<<<dim3((N + 127) / 128, 8), 256, 0, stream>>>(
        h_bf, w_bf + (size_t)l * 65536, w_bf + 196608 + (size_t)l * 65536,
        bl_c + l * 512, br_c + l * 512, comb, N);
    gat_fused<<<(N + 3) / 4, 256, 0, stream>>>(comb, att_c + l * 512, offs, csr_src,
        cb_c + l * 128, g_c + l * 128, b_c + l * 128, h_f32, h_bf, N);
  }
  pool<<<B * 8, 128, 0, stream>>>(h_f32, bat32, N, g_sum);
  mlp_head<<<B, 256, 0, stream>>>(g_sum, bat32, N, W1_c, b1_c, W2_c, b2_c, og_c, ob_c, d_out, flags);
}